// Round 11
// baseline (232.089 us; speedup 1.0000x reference)
//
#include <hip/hip_runtime.h>
#include <stdint.h>

#define M_TOTAL 16384
#define N_TOTAL 1024
#define K_TOTAL 1024
#define BM 256
#define BN 256
#define BK 64
#define NTILES (K_TOTAL / BK)       // 16
#define NWG ((M_TOTAL / BM) * (N_TOTAL / BN))   // 256

using f32x4  = __attribute__((ext_vector_type(4))) float;
using bf16x8 = __attribute__((ext_vector_type(8))) short;
using bf16x4 = __attribute__((ext_vector_type(4))) short;

#define AS1 __attribute__((address_space(1)))
#define AS3 __attribute__((address_space(3)))
#define SB() __builtin_amdgcn_sched_barrier(0)

__device__ __forceinline__ unsigned packrne(float x, float y) {
    unsigned ux = __builtin_bit_cast(unsigned, x);
    unsigned uy = __builtin_bit_cast(unsigned, y);
    ux += 0x7fffu + ((ux >> 16) & 1u);
    uy += 0x7fffu + ((uy >> 16) & 1u);
    return (ux >> 16) | (uy & 0xffff0000u);
}

// ---------------- kernel 1: W fp32 -> bf16 (4 MB read / 2 MB write) ---------
#define N8W (N_TOTAL * K_TOTAL / 8)   // 131072
__global__ __launch_bounds__(256) void cvtW_kernel(
    const float* __restrict__ W, uint4* __restrict__ Wb)
{
    const int i = blockIdx.x * 256 + threadIdx.x;
    const f32x4* p = (const f32x4*)W + (size_t)i * 2;
    const f32x4 a = p[0], b = p[1];
    uint4 r;
    r.x = packrne(a[0], a[1]);
    r.y = packrne(a[2], a[3]);
    r.z = packrne(b[0], b[1]);
    r.w = packrne(b[2], b[3]);
    Wb[i] = r;
}

// ---------------- kernel 2: fused GEMM, 16 waves, low per-wave registers ----
// C[m][n] = sum_k X[m][k]*W[n][k] + bias[n].  256x256 tile, BK=64, 1024 thr
// = 16 waves (4M x 4N), wave-tile 64x64 -> acc = 64 AGPR/wave, arch ~115.
// r9's verified schedule: per tile {B1 barrier -> write_A(A(t+1)) [reg-wait =
// counted vmcnt, retires older B(t) gloads] + stage_B(t+1) -> lgkm0 -> B2
// barrier -> compute (issues load_A(t+2))}.  A held fp32 in regs 1 tile,
// converted at write.  LDS rows 128B, 16B slot s of row r holds kg = s^(r&7)
// (B: linear gload_lds dest + pre-swizzled source; A: swizzled ds_write).
__global__ __launch_bounds__(1024) void gemm16w_kernel(
    const float* __restrict__ X, const unsigned short* __restrict__ Wb,
    const float* __restrict__ bias, float* __restrict__ C)
{
    __shared__ __align__(16) char smem[131072]; // A0@0 A1@32768 B0@65536 B1@98304

    const int tid  = threadIdx.x;
    const int lane = tid & 63;
    const int wave = tid >> 6;      // 0..15
    const int wr = wave >> 2;       // 0..3 : 64-row strip
    const int wc = wave & 3;        // 0..3 : 64-col strip

    // XCD-chunked swizzle (verified r2-r10)
    const int bid  = blockIdx.x;
    const int work = (bid & 7) * (NWG / 8) + (bid >> 3);
    const int bm = work >> 2;
    const int bn = work & 3;
    const int m0 = bm * BM, n0 = bn * BN;

    // ---- B staging: gload_lds, linear dest + pre-swizzled source -----------
    const int kge = ((lane & 7) ^ ((lane >> 3) & 7)) * 8;
    auto stage_B = [&](int t, int b) {
        #pragma unroll
        for (int j = 0; j < 2; ++j) {
            const int rb = wave * 16 + j * 8;      // 8-row block base
            __builtin_amdgcn_global_load_lds(
                (const AS1 void*)(Wb + (size_t)(n0 + rb + (lane >> 3)) * K_TOTAL
                                     + t * BK + kge),
                (AS3 void*)(smem + 65536 + b * 32768 + rb * 128), 16, 0, 0);
        }
    };

    // ---- A staging: 16 fp32/thread, loaded 1 tile early, cvt at write ------
    const int arow  = tid >> 2;     // 0..255
    const int achk  = tid & 3;      // 16-float chunk within the 64-k row
    const int ars   = arow & 7;
    auto load_A = [&](int t, f32x4 (&v)[4]) {
        const f32x4* p = (const f32x4*)(X + (size_t)(m0 + arow) * K_TOTAL
                                          + t * BK + achk * 16);
        #pragma unroll
        for (int i = 0; i < 4; ++i) v[i] = p[i];
    };
    auto write_A = [&](int b, const f32x4 (&v)[4]) {
        #pragma unroll
        for (int j = 0; j < 2; ++j) {
            uint4 c;
            c.x = packrne(v[2 * j][0], v[2 * j][1]);
            c.y = packrne(v[2 * j][2], v[2 * j][3]);
            c.z = packrne(v[2 * j + 1][0], v[2 * j + 1][1]);
            c.w = packrne(v[2 * j + 1][2], v[2 * j + 1][3]);
            const int kg = achk * 2 + j;
            *(uint4*)(smem + b * 32768 + arow * 128 + ((kg ^ ars) << 4)) = c;
        }
    };

    const int cl = lane & 15;
    const int kb = lane >> 4;       // 0..3

    f32x4 acc[4][4] = {};

#define BARRIER() SB(); __builtin_amdgcn_s_barrier(); SB()
#define LGKM0()   asm volatile("s_waitcnt lgkmcnt(0)" ::: "memory"); SB()
#define VM0()     asm volatile("s_waitcnt vmcnt(0)" ::: "memory"); SB()

    // ---- compute: wave 64x64, 2 col-phases (frag pressure <= 48 regs) ------
    auto compute_tile = [&](int buf, f32x4 (&L)[4], bool doload, int tload) {
        if (doload) load_A(tload, L);
        const char* Ab = smem + buf * 32768;
        const char* Bb = smem + 65536 + buf * 32768;
        bf16x8 aF[4][2], bF[2][2];

        #pragma unroll
        for (int i = 0; i < 4; ++i) {
            const int q = wr * 64 + i * 16 + cl;
            const int qs = q & 7;
            aF[i][0] = *(const bf16x8*)(Ab + q * 128 + ((kb       ^ qs) << 4));
            aF[i][1] = *(const bf16x8*)(Ab + q * 128 + (((kb + 4) ^ qs) << 4));
        }
        // col phase 0: cols 0-31
        #pragma unroll
        for (int jj = 0; jj < 2; ++jj) {
            const int p = wc * 64 + jj * 16 + cl;
            const int ps = p & 7;
            bF[jj][0] = *(const bf16x8*)(Bb + p * 128 + ((kb       ^ ps) << 4));
            bF[jj][1] = *(const bf16x8*)(Bb + p * 128 + (((kb + 4) ^ ps) << 4));
        }
        __builtin_amdgcn_s_setprio(1);
        #pragma unroll
        for (int i = 0; i < 4; ++i)
            #pragma unroll
            for (int jj = 0; jj < 2; ++jj) {
                acc[i][jj] = __builtin_amdgcn_mfma_f32_16x16x32_bf16(aF[i][0], bF[jj][0], acc[i][jj], 0, 0, 0);
                acc[i][jj] = __builtin_amdgcn_mfma_f32_16x16x32_bf16(aF[i][1], bF[jj][1], acc[i][jj], 0, 0, 0);
            }
        __builtin_amdgcn_s_setprio(0);
        // col phase 1: cols 32-63 (reuse bF regs)
        #pragma unroll
        for (int jj = 0; jj < 2; ++jj) {
            const int p = wc * 64 + 32 + jj * 16 + cl;
            const int ps = p & 7;
            bF[jj][0] = *(const bf16x8*)(Bb + p * 128 + ((kb       ^ ps) << 4));
            bF[jj][1] = *(const bf16x8*)(Bb + p * 128 + (((kb + 4) ^ ps) << 4));
        }
        __builtin_amdgcn_s_setprio(1);
        #pragma unroll
        for (int i = 0; i < 4; ++i)
            #pragma unroll
            for (int jj = 0; jj < 2; ++jj) {
                acc[i][2 + jj] = __builtin_amdgcn_mfma_f32_16x16x32_bf16(aF[i][0], bF[jj][0], acc[i][2 + jj], 0, 0, 0);
                acc[i][2 + jj] = __builtin_amdgcn_mfma_f32_16x16x32_bf16(aF[i][1], bF[jj][1], acc[i][2 + jj], 0, 0, 0);
            }
        __builtin_amdgcn_s_setprio(0);
    };

    // ---- prologue ----------------------------------------------------------
    // B(0) issued BEFORE the A loads -> write_A's implicit wait on aP (newer)
    // retires B(0) too; aQ stays in flight across the first barrier.
    f32x4 aP[4], aQ[4];
    stage_B(0, 0);
    load_A(0, aP);
    load_A(1, aQ);
    write_A(0, aP);
    LGKM0();

    // ---- main loop (2x unrolled for static reg ping-pong) ------------------
    #pragma unroll 1
    for (int t = 0; t < NTILES; t += 2) {
        // tile t (buf 0)
        BARRIER();                                   // B1: buf1 free
        write_A(1, aQ);                              // A(t+1); reg-wait retires B(t)
        stage_B(t + 1, 1);
        LGKM0();
        BARRIER();                                   // B2: tile t ready
        compute_tile(0, aP, t + 2 < NTILES, t + 2);  // loads A(t+2) -> aP

        // tile t+1 (buf 1)
        BARRIER();                                   // B1: buf0 free
        if (t + 2 < NTILES) {
            write_A(0, aP);                          // A(t+2); reg-wait retires B(t+1)
            stage_B(t + 2, 0);
            LGKM0();
        } else {
            VM0();                                   // force B(t+1) for final tile
        }
        BARRIER();                                   // B2: tile t+1 ready
        compute_tile(1, aQ, t + 3 < NTILES, t + 3);  // loads A(t+3) -> aQ
    }

    // ---- epilogue: D element (row=(lane>>4)*4+r, col=lane&15) [m89] --------
    const int r0 = (lane >> 4) * 4;
    #pragma unroll
    for (int ni = 0; ni < 4; ++ni) {
        const int n = n0 + wc * 64 + ni * 16 + cl;
        const float bvv = bias[n];
        #pragma unroll
        for (int mi = 0; mi < 4; ++mi) {
            const int m = m0 + wr * 64 + mi * 16 + r0;
            #pragma unroll
            for (int r = 0; r < 4; ++r)
                C[(size_t)(m + r) * N_TOTAL + n] = acc[mi][ni][r] + bvv;
        }
    }
#undef BARRIER
#undef LGKM0
#undef VM0
}

// ---------------- fallback: round-1 single kernel (known-good) --------------
__device__ __forceinline__ short f2bf(float f) {
    unsigned u = __builtin_bit_cast(unsigned, f);
    u += 0x7fffu + ((u >> 16) & 1u);
    return (short)(u >> 16);
}

#define FBM 128
#define FBN 128
#define FNWG ((M_TOTAL / FBM) * (N_TOTAL / FBN))   // 1024

__global__ __launch_bounds__(256) void fb_gemm_bias_kernel(
    const float* __restrict__ X, const float* __restrict__ W,
    const float* __restrict__ bias, float* __restrict__ C)
{
    __shared__ short As[FBM * BK];
    __shared__ short Bs[FBN * BK];

    const int tid  = threadIdx.x;
    const int lane = tid & 63;
    const int wave = tid >> 6;
    const int wr = wave >> 1;
    const int wc = wave & 1;

    const int bid  = blockIdx.x;
    const int work = (bid & 7) * (FNWG / 8) + (bid >> 3);
    const int bm = work >> 3;
    const int bn = work & 7;
    const int m0 = bm * FBM, n0 = bn * FBN;

    const int srow  = tid >> 4;
    const int scol4 = tid & 15;

    f32x4 acc[4][4] = {};
    char* const Ab = (char*)As;
    char* const Bb = (char*)Bs;

    for (int k0 = 0; k0 < K_TOTAL; k0 += BK) {
        __syncthreads();
        #pragma unroll
        for (int pass = 0; pass < 8; ++pass) {
            const int row = srow + pass * 16;
            const int off = (row * (BK * 2) + scol4 * 8) ^ ((row & 7) << 4);
            {
                const f32x4 v = *(const f32x4*)(X + (size_t)(m0 + row) * K_TOTAL + k0 + scol4 * 4);
                bf16x4 b;
                b[0] = f2bf(v[0]); b[1] = f2bf(v[1]); b[2] = f2bf(v[2]); b[3] = f2bf(v[3]);
                *(bf16x4*)(Ab + off) = b;
            }
            {
                const f32x4 v = *(const f32x4*)(W + (size_t)(n0 + row) * K_TOTAL + k0 + scol4 * 4);
                bf16x4 b;
                b[0] = f2bf(v[0]); b[1] = f2bf(v[1]); b[2] = f2bf(v[2]); b[3] = f2bf(v[3]);
                *(bf16x4*)(Bb + off) = b;
            }
        }
        __syncthreads();

        #pragma unroll
        for (int ks = 0; ks < 2; ++ks) {
            const int kel = ks * 32 + ((lane >> 4) << 3);
            bf16x8 af[4], bfr[4];
            #pragma unroll
            for (int i = 0; i < 4; ++i) {
                const int ar = wr * 64 + i * 16 + (lane & 15);
                af[i]  = *(const bf16x8*)(Ab + ((ar * (BK * 2) + kel * 2) ^ ((ar & 7) << 4)));
                const int br = wc * 64 + i * 16 + (lane & 15);
                bfr[i] = *(const bf16x8*)(Bb + ((br * (BK * 2) + kel * 2) ^ ((br & 7) << 4)));
            }
            #pragma unroll
            for (int mi = 0; mi < 4; ++mi)
                #pragma unroll
                for (int ni = 0; ni < 4; ++ni)
                    acc[mi][ni] = __builtin_amdgcn_mfma_f32_16x16x32_bf16(
                        af[mi], bfr[ni], acc[mi][ni], 0, 0, 0);
        }
    }

    const int cl = lane & 15;
    const int r0 = (lane >> 4) * 4;
    #pragma unroll
    for (int ni = 0; ni < 4; ++ni) {
        const int n = n0 + wc * 64 + ni * 16 + cl;
        const float bvv = bias[n];
        #pragma unroll
        for (int mi = 0; mi < 4; ++mi) {
            const int m = m0 + wr * 64 + mi * 16 + r0;
            #pragma unroll
            for (int r = 0; r < 4; ++r)
                C[(size_t)(m + r) * N_TOTAL + n] = acc[mi][ni][r] + bvv;
        }
    }
}

extern "C" void kernel_launch(void* const* d_in, const int* in_sizes, int n_in,
                              void* d_out, int out_size, void* d_ws, size_t ws_size,
                              hipStream_t stream) {
    // inputs: 0:X 1:Wq 2:bq 3:Wk 4:bk 5:Wv 6:bv
    // softmax rows sum to 1 => out = X @ Wv^T + bv exactly.
    const float* X  = (const float*)d_in[0];
    const float* Wv = (const float*)d_in[5];
    const float* bv = (const float*)d_in[6];
    float* out = (float*)d_out;

    const size_t WB_BYTES = (size_t)N_TOTAL * K_TOTAL * 2;   // 2 MiB

    if (ws_size >= WB_BYTES) {
        unsigned short* Wb = (unsigned short*)d_ws;
        cvtW_kernel<<<dim3(N8W / 256), dim3(256), 0, stream>>>(Wv, (uint4*)Wb);
        gemm16w_kernel<<<dim3(NWG), dim3(1024), 0, stream>>>(X, Wb, bv, out);
    } else {
        fb_gemm_bias_kernel<<<dim3(FNWG), dim3(256), 0, stream>>>(X, Wv, bv, out);
    }
}

// Round 12
// 59.806 us; speedup vs baseline: 3.8807x; 3.8807x over previous
//
#include <hip/hip_runtime.h>
#include <stdint.h>

#define M_TOTAL 16384
#define N_TOTAL 1024
#define K_TOTAL 1024
#define BM 128
#define BN 128
#define BK 64
#define NTILES (K_TOTAL / BK)                 // 16
#define NWG ((M_TOTAL / BM) * (N_TOTAL / BN)) // 1024

using f32x4  = __attribute__((ext_vector_type(4))) float;
using bf16x8 = __attribute__((ext_vector_type(8))) short;
using bf16x4 = __attribute__((ext_vector_type(4))) short;

#define AS1 __attribute__((address_space(1)))
#define AS3 __attribute__((address_space(3)))
#define SB() __builtin_amdgcn_sched_barrier(0)

__device__ __forceinline__ unsigned packrne(float x, float y) {
    unsigned ux = __builtin_bit_cast(unsigned, x);
    unsigned uy = __builtin_bit_cast(unsigned, y);
    ux += 0x7fffu + ((ux >> 16) & 1u);
    uy += 0x7fffu + ((uy >> 16) & 1u);
    return (ux >> 16) | (uy & 0xffff0000u);
}

// ---------------- kernel 1: fused fp32->bf16 convert of X and Wv (r4) -------
#define N8X (M_TOTAL * K_TOTAL / 8)   // 2097152
#define N8W (N_TOTAL * K_TOTAL / 8)   // 131072
__global__ __launch_bounds__(256) void cvt2_kernel(
    const float* __restrict__ X, const float* __restrict__ W,
    uint4* __restrict__ Xb, uint4* __restrict__ Wb)
{
    const int i = blockIdx.x * 256 + threadIdx.x;
    const float* src; uint4* dst; int idx;
    if (i < N8X) { src = X; dst = Xb; idx = i; }
    else         { src = W; dst = Wb; idx = i - N8X; }
    const f32x4* p = (const f32x4*)src + (size_t)idx * 2;
    const f32x4 a = p[0], b = p[1];
    uint4 r;
    r.x = packrne(a[0], a[1]);
    r.y = packrne(a[2], a[3]);
    r.z = packrne(b[0], b[1]);
    r.w = packrne(b[2], b[3]);
    dst[idx] = r;
}

// ---------------- kernel 2: 128x128 counted-vmcnt GEMM, 2 blocks/CU ---------
// C[m][n] = sum_k Xb[m][k]*Wb[n][k] + bias[n].  bf16 inputs from ws.
// 4 waves (2M x 2N, wave-tile 64x64), BK=64, LDS 64KB dbuf -> 2 blocks/CU
// (the single isolated change vs r4's 256^2/1-block: cross-block overlap).
// Per tile: B1 barrier (prev compute done reading nbuf) -> stage A,B(t+1)
// into nbuf (8 gload_lds) -> VM(8) counted (retires tile-t's 8; t+1's fly)
// -> B2 barrier -> compute tile t (2 k-half phases, 16 MFMA each, setprio).
// LDS: row r (128B) holds k-group kg at 16B slot kg^(r&7); linear gload_lds
// dest + pre-swizzled global source (r4-proven, 0 bank conflicts).
__global__ __launch_bounds__(256) void gemm2b_kernel(
    const unsigned short* __restrict__ Xb, const unsigned short* __restrict__ Wb,
    const float* __restrict__ bias, float* __restrict__ C)
{
    __shared__ __align__(16) char smem[65536]; // A0@0 A1@16384 B0@32768 B1@49152

    const int tid  = threadIdx.x;
    const int lane = tid & 63;
    const int wave = tid >> 6;      // 0..3
    const int wr = wave >> 1;       // 0..1 : 64-row strip
    const int wc = wave & 1;        // 0..1 : 64-col strip

    // XCD-chunked swizzle (verified r2-r11)
    const int bid  = blockIdx.x;
    const int work = (bid & 7) * (NWG / 8) + (bid >> 3);
    const int bm = work >> 3;
    const int bn = work & 7;
    const int m0 = bm * BM, n0 = bn * BN;

    // staging: issue j covers 32 rows; wave w rows j*32+w*8..+8; lane l ->
    // row +(l>>3), slot l&7; source k-group (l&7)^((l>>3)&7) (pre-swizzle).
    const int srow = wave * 8 + (lane >> 3);                // row in 32-stripe
    const int kge  = ((lane & 7) ^ ((lane >> 3) & 7)) * 8;  // swizzled k elems

    auto stage = [&](int t, int b) {
        #pragma unroll
        for (int j = 0; j < 4; ++j) {   // A: 4 x 32 rows
            __builtin_amdgcn_global_load_lds(
                (const AS1 void*)(Xb + (size_t)(m0 + j * 32 + srow) * K_TOTAL
                                     + t * BK + kge),
                (AS3 void*)(smem + b * 16384 + j * 4096 + wave * 1024),
                16, 0, 0);
        }
        #pragma unroll
        for (int j = 0; j < 4; ++j) {   // B: 4 x 32 rows
            __builtin_amdgcn_global_load_lds(
                (const AS1 void*)(Wb + (size_t)(n0 + j * 32 + srow) * K_TOTAL
                                     + t * BK + kge),
                (AS3 void*)(smem + 32768 + b * 16384 + j * 4096 + wave * 1024),
                16, 0, 0);
        }
    };

    const int cl = lane & 15;
    const int kb = lane >> 4;       // 0..3

    f32x4 acc[4][4] = {};

#define BARRIER() SB(); __builtin_amdgcn_s_barrier(); SB()
#define VM(N)     asm volatile("s_waitcnt vmcnt(" #N ")" ::: "memory"); SB()

    auto compute_tile = [&](int buf) {
        const char* Ab = smem + buf * 16384;
        const char* Bb = smem + 32768 + buf * 16384;
        #pragma unroll
        for (int ks = 0; ks < 2; ++ks) {
            const int kg = ks * 4 + kb;
            bf16x8 aF[4], bF[4];
            #pragma unroll
            for (int i = 0; i < 4; ++i) {
                const int ar = wr * 64 + i * 16 + cl;
                aF[i] = *(const bf16x8*)(Ab + ar * 128 + ((kg ^ (ar & 7)) << 4));
                const int br = wc * 64 + i * 16 + cl;
                bF[i] = *(const bf16x8*)(Bb + br * 128 + ((kg ^ (br & 7)) << 4));
            }
            __builtin_amdgcn_s_setprio(1);
            #pragma unroll
            for (int i = 0; i < 4; ++i)
                #pragma unroll
                for (int j = 0; j < 4; ++j)
                    acc[i][j] = __builtin_amdgcn_mfma_f32_16x16x32_bf16(
                        aF[i], bF[j], acc[i][j], 0, 0, 0);
            __builtin_amdgcn_s_setprio(0);
        }
    };

    // ---- prologue: tiles 0 and 1 staged; tile 0 landed, tile 1 in flight ---
    stage(0, 0);
    stage(1, 1);
    VM(8);
    BARRIER();
    compute_tile(0);

    // ---- main loop ---------------------------------------------------------
    #pragma unroll 1
    for (int t = 1; t < NTILES; ++t) {
        const int buf = t & 1, nbuf = buf ^ 1;
        BARRIER();                          // B1: all waves done reading nbuf
        if (t + 1 < NTILES) {
            stage(t + 1, nbuf);
            VM(8);                          // retire tile-t's 8; t+1's fly
        } else {
            VM(0);                          // final tile: drain
        }
        BARRIER();                          // B2: tile t fully in LDS
        compute_tile(buf);
    }

    // ---- epilogue: D element (row=(lane>>4)*4+r, col=lane&15) [m89] --------
    const int r0 = (lane >> 4) * 4;
    #pragma unroll
    for (int ni = 0; ni < 4; ++ni) {
        const int n = n0 + wc * 64 + ni * 16 + cl;
        const float bvv = bias[n];
        #pragma unroll
        for (int mi = 0; mi < 4; ++mi) {
            const int m = m0 + wr * 64 + mi * 16 + r0;
            #pragma unroll
            for (int r = 0; r < 4; ++r)
                C[(size_t)(m + r) * N_TOTAL + n] = acc[mi][ni][r] + bvv;
        }
    }
#undef BARRIER
#undef VM
}

// ---------------- fallback: round-1 single kernel (known-good) --------------
__device__ __forceinline__ short f2bf(float f) {
    unsigned u = __builtin_bit_cast(unsigned, f);
    u += 0x7fffu + ((u >> 16) & 1u);
    return (short)(u >> 16);
}

__global__ __launch_bounds__(256) void fb_gemm_bias_kernel(
    const float* __restrict__ X, const float* __restrict__ W,
    const float* __restrict__ bias, float* __restrict__ C)
{
    __shared__ short As[BM * BK];
    __shared__ short Bs[BN * BK];

    const int tid  = threadIdx.x;
    const int lane = tid & 63;
    const int wave = tid >> 6;
    const int wr = wave >> 1;
    const int wc = wave & 1;

    const int bid  = blockIdx.x;
    const int work = (bid & 7) * (NWG / 8) + (bid >> 3);
    const int bm = work >> 3;
    const int bn = work & 7;
    const int m0 = bm * BM, n0 = bn * BN;

    const int srow  = tid >> 4;
    const int scol4 = tid & 15;

    f32x4 acc[4][4] = {};
    char* const Ab = (char*)As;
    char* const Bb = (char*)Bs;

    for (int k0 = 0; k0 < K_TOTAL; k0 += BK) {
        __syncthreads();
        #pragma unroll
        for (int pass = 0; pass < 8; ++pass) {
            const int row = srow + pass * 16;
            const int off = (row * (BK * 2) + scol4 * 8) ^ ((row & 7) << 4);
            {
                const f32x4 v = *(const f32x4*)(X + (size_t)(m0 + row) * K_TOTAL + k0 + scol4 * 4);
                bf16x4 b;
                b[0] = f2bf(v[0]); b[1] = f2bf(v[1]); b[2] = f2bf(v[2]); b[3] = f2bf(v[3]);
                *(bf16x4*)(Ab + off) = b;
            }
            {
                const f32x4 v = *(const f32x4*)(W + (size_t)(n0 + row) * K_TOTAL + k0 + scol4 * 4);
                bf16x4 b;
                b[0] = f2bf(v[0]); b[1] = f2bf(v[1]); b[2] = f2bf(v[2]); b[3] = f2bf(v[3]);
                *(bf16x4*)(Bb + off) = b;
            }
        }
        __syncthreads();

        #pragma unroll
        for (int ks = 0; ks < 2; ++ks) {
            const int kel = ks * 32 + ((lane >> 4) << 3);
            bf16x8 af[4], bfr[4];
            #pragma unroll
            for (int i = 0; i < 4; ++i) {
                const int ar = wr * 64 + i * 16 + (lane & 15);
                af[i]  = *(const bf16x8*)(Ab + ((ar * (BK * 2) + kel * 2) ^ ((ar & 7) << 4)));
                const int br = wc * 64 + i * 16 + (lane & 15);
                bfr[i] = *(const bf16x8*)(Bb + ((br * (BK * 2) + kel * 2) ^ ((br & 7) << 4)));
            }
            #pragma unroll
            for (int mi = 0; mi < 4; ++mi)
                #pragma unroll
                for (int ni = 0; ni < 4; ++ni)
                    acc[mi][ni] = __builtin_amdgcn_mfma_f32_16x16x32_bf16(
                        af[mi], bfr[ni], acc[mi][ni], 0, 0, 0);
        }
    }

    const int cl = lane & 15;
    const int r0 = (lane >> 4) * 4;
    #pragma unroll
    for (int ni = 0; ni < 4; ++ni) {
        const int n = n0 + wc * 64 + ni * 16 + cl;
        const float bvv = bias[n];
        #pragma unroll
        for (int mi = 0; mi < 4; ++mi) {
            const int m = m0 + wr * 64 + mi * 16 + r0;
            #pragma unroll
            for (int r = 0; r < 4; ++r)
                C[(size_t)(m + r) * N_TOTAL + n] = acc[mi][ni][r] + bvv;
        }
    }
}

extern "C" void kernel_launch(void* const* d_in, const int* in_sizes, int n_in,
                              void* d_out, int out_size, void* d_ws, size_t ws_size,
                              hipStream_t stream) {
    // inputs: 0:X 1:Wq 2:bq 3:Wk 4:bk 5:Wv 6:bv
    // softmax rows sum to 1 => out = X @ Wv^T + bv exactly.
    const float* X  = (const float*)d_in[0];
    const float* Wv = (const float*)d_in[5];
    const float* bv = (const float*)d_in[6];
    float* out = (float*)d_out;

    const size_t XB_BYTES = (size_t)M_TOTAL * K_TOTAL * 2;   // 32 MiB
    const size_t WB_BYTES = (size_t)N_TOTAL * K_TOTAL * 2;   // 2 MiB

    if (ws_size >= XB_BYTES + WB_BYTES) {
        unsigned short* Xb = (unsigned short*)d_ws;
        unsigned short* Wb = (unsigned short*)((char*)d_ws + XB_BYTES);
        cvt2_kernel<<<dim3((N8X + N8W) / 256), dim3(256), 0, stream>>>(
            X, Wv, (uint4*)Xb, (uint4*)Wb);
        gemm2b_kernel<<<dim3(NWG), dim3(256), 0, stream>>>(Xb, Wb, bv, out);
    } else {
        fb_gemm_bias_kernel<<<dim3(NWG), dim3(256), 0, stream>>>(X, Wv, bv, out);
    }
}